// Round 5
// baseline (1359.206 us; speedup 1.0000x reference)
//
#include <hip/hip_runtime.h>
#include <hip/hip_bf16.h>

// ---- problem constants ----
#define BSZ 2
#define LSEQ 1024
#define DMODEL 768
#define NLAYER 4
#define DINNER 1536
#define DSTATE 16
#define DCONV 4
#define DTRANK 48
// chunked scan: 64 chunks of 16 steps
#define NCHUNK 64
#define CLEN 16
// xdbl row stride (N=80 padded to 128 for the MFMA path)
#define XDSTR 128

typedef __bf16 bf16x8_t __attribute__((ext_vector_type(8)));
typedef float f32x4_t __attribute__((ext_vector_type(4)));
typedef __hip_bfloat16 bf16;

// ---------------- block reduce ----------------
__device__ inline float block_reduce_sum(float v, float* sbuf) {
    __syncthreads();
    #pragma unroll
    for (int o = 32; o > 0; o >>= 1) v += __shfl_down(v, o, 64);
    int wid = threadIdx.x >> 6;
    int lane = threadIdx.x & 63;
    if (lane == 0) sbuf[wid] = v;
    __syncthreads();
    if (threadIdx.x == 0) sbuf[0] = (sbuf[0] + sbuf[1]) + (sbuf[2] + sbuf[3]);
    __syncthreads();
    return sbuf[0];
}

// ---------------- embedding ----------------
__global__ __launch_bounds__(256) void embed_kernel(
    const int* __restrict__ seq, const float* __restrict__ emb, float* __restrict__ res) {
    int idx = blockIdx.x * 256 + threadIdx.x;  // < B*L*DMODEL
    int bl = idx / DMODEL;
    int dd = idx - bl * DMODEL;
    res[idx] = emb[(size_t)seq[bl] * DMODEL + dd];
}

// ---------------- rmsnorm (per row) ----------------
__global__ __launch_bounds__(256) void rmsnorm_kernel(
    const float* __restrict__ res, const float* __restrict__ w, float* __restrict__ out) {
    __shared__ float sbuf[8];
    int row = blockIdx.x;
    const float* x = res + (size_t)row * DMODEL;
    float ss = 0.f;
    for (int i = threadIdx.x; i < DMODEL; i += 256) { float v = x[i]; ss += v * v; }
    ss = block_reduce_sum(ss, sbuf);
    float scale = rsqrtf(ss / (float)DMODEL + 1e-5f);
    for (int i = threadIdx.x; i < DMODEL; i += 256)
        out[(size_t)row * DMODEL + i] = x[i] * scale * w[i];
}

// ---------------- weight padding (once per launch) ----------------
__global__ __launch_bounds__(256) void pad_xp_kernel(
    const float* __restrict__ xp_w, float* __restrict__ xp_pad) {
    int idx = blockIdx.x * 256 + threadIdx.x;  // < NLAYER*128*1536
    int k = idx % DINNER;
    int e = (idx / DINNER) % 128;
    int l = idx / (DINNER * 128);
    xp_pad[idx] = (e < 80) ? xp_w[((size_t)l * 80 + e) * DINNER + k] : 0.f;
}

__global__ __launch_bounds__(256) void pad_dt_kernel(
    const float* __restrict__ dt_w, float* __restrict__ dt_pad) {
    int idx = blockIdx.x * 256 + threadIdx.x;  // < NLAYER*1536*64
    int k = idx % 64;
    int d = (idx / 64) % DINNER;
    int l = idx / (64 * DINNER);
    dt_pad[idx] = (k < DTRANK) ? dt_w[((size_t)l * DINNER + d) * DTRANK + k] : 0.f;
}

// stage 16 f32 -> 16 bf16 into LDS
__device__ inline void stage16(const float* __restrict__ g, bf16* __restrict__ l) {
    float4 v0 = ((const float4*)g)[0];
    float4 v1 = ((const float4*)g)[1];
    float4 v2 = ((const float4*)g)[2];
    float4 v3 = ((const float4*)g)[3];
    bf16x8_t p0, p1;
    p0[0] = (__bf16)v0.x; p0[1] = (__bf16)v0.y; p0[2] = (__bf16)v0.z; p0[3] = (__bf16)v0.w;
    p0[4] = (__bf16)v1.x; p0[5] = (__bf16)v1.y; p0[6] = (__bf16)v1.z; p0[7] = (__bf16)v1.w;
    p1[0] = (__bf16)v2.x; p1[1] = (__bf16)v2.y; p1[2] = (__bf16)v2.z; p1[3] = (__bf16)v2.w;
    p1[4] = (__bf16)v3.x; p1[5] = (__bf16)v3.y; p1[6] = (__bf16)v3.z; p1[7] = (__bf16)v3.w;
    *(bf16x8_t*)(l) = p0;
    *(bf16x8_t*)(l + 8) = p1;
}

// ---------------- GEMM NT 64x64 tile (for small-N shapes) ----------------
// mode 0: C = acc; mode 1: C += acc; mode 2: C = softplus(acc + bias[n]).
__global__ __launch_bounds__(256) void gemm_nt(
    const float* __restrict__ A, int lda, const float* __restrict__ Bw, int ldb,
    float* __restrict__ Cout, int ldc, const float* __restrict__ bias,
    int M, int N, int K, int mode) {
    __shared__ bf16 As[64][72];
    __shared__ bf16 Bs[64][72];
    int tid = threadIdx.x;
    int wave = tid >> 6;
    int lane = tid & 63;
    int quad = lane >> 4;
    int l16 = lane & 15;
    int bm = blockIdx.x * 64;
    int bn = blockIdx.y * 64;
    int lrow = tid >> 2;           // 0..63
    int lc = (tid & 3) * 16;       // 0,16,32,48

    f32x4_t acc[4];
    #pragma unroll
    for (int i = 0; i < 4; ++i) acc[i] = (f32x4_t){0.f, 0.f, 0.f, 0.f};

    for (int k0 = 0; k0 < K; k0 += 64) {
        stage16(A + (size_t)(bm + lrow) * lda + k0 + lc, &As[lrow][lc]);
        stage16(Bw + (size_t)(bn + lrow) * ldb + k0 + lc, &Bs[lrow][lc]);
        __syncthreads();
        #pragma unroll
        for (int kk = 0; kk < 64; kk += 32) {
            bf16x8_t af = *(const bf16x8_t*)(&As[wave * 16 + l16][kk + quad * 8]);
            #pragma unroll
            for (int i = 0; i < 4; ++i) {
                bf16x8_t bfv = *(const bf16x8_t*)(&Bs[i * 16 + l16][kk + quad * 8]);
                acc[i] = __builtin_amdgcn_mfma_f32_16x16x32_bf16(af, bfv, acc[i], 0, 0, 0);
            }
        }
        __syncthreads();
    }

    int m0 = bm + wave * 16 + quad * 4;
    #pragma unroll
    for (int i = 0; i < 4; ++i) {
        int n = bn + i * 16 + l16;
        if (mode == 0) {
            #pragma unroll
            for (int r = 0; r < 4; ++r)
                Cout[(size_t)(m0 + r) * ldc + n] = acc[i][r];
        } else if (mode == 1) {
            #pragma unroll
            for (int r = 0; r < 4; ++r)
                Cout[(size_t)(m0 + r) * ldc + n] += acc[i][r];
        } else {
            float bv = bias[n];
            #pragma unroll
            for (int r = 0; r < 4; ++r) {
                float v = acc[i][r] + bv;
                Cout[(size_t)(m0 + r) * ldc + n] = (v > 20.f) ? v : log1pf(__expf(v));
            }
        }
    }
}

// ---------------- GEMM NT 128x128 tile ----------------
// 4 waves, each computes a 64x64 quadrant (4x4 grid of 16x16 MFMA tiles).
// A: M x K (row stride lda) f32; Bw: N x K (row stride ldb) f32.
// mode 0: C = acc; mode 1: C += acc; mode 2: C = softplus(acc + bias[n]).
// M%128==0, N%128==0, K%64==0.
__global__ __launch_bounds__(256) void gemm128(
    const float* __restrict__ A, int lda, const float* __restrict__ Bw, int ldb,
    float* __restrict__ Cout, int ldc, const float* __restrict__ bias,
    int M, int N, int K, int mode) {
    __shared__ bf16 As[128][72];
    __shared__ bf16 Bs[128][72];
    int tid = threadIdx.x;
    int wave = tid >> 6;
    int lane = tid & 63;
    int quad = lane >> 4;
    int l16 = lane & 15;
    int bm = blockIdx.x * 128;
    int bn = blockIdx.y * 128;
    int wm = (wave & 1) * 64;
    int wn = (wave >> 1) * 64;
    int srow = tid >> 1;           // 0..127
    int scol = (tid & 1) * 32;     // 0 or 32

    f32x4_t acc[4][4];
    #pragma unroll
    for (int i = 0; i < 4; ++i)
        #pragma unroll
        for (int j = 0; j < 4; ++j) acc[i][j] = (f32x4_t){0.f, 0.f, 0.f, 0.f};

    for (int k0 = 0; k0 < K; k0 += 64) {
        const float* ag = A + (size_t)(bm + srow) * lda + k0 + scol;
        const float* bg = Bw + (size_t)(bn + srow) * ldb + k0 + scol;
        stage16(ag, &As[srow][scol]);
        stage16(ag + 16, &As[srow][scol + 16]);
        stage16(bg, &Bs[srow][scol]);
        stage16(bg + 16, &Bs[srow][scol + 16]);
        __syncthreads();
        #pragma unroll
        for (int kk = 0; kk < 64; kk += 32) {
            bf16x8_t af[4], bfr[4];
            #pragma unroll
            for (int i = 0; i < 4; ++i)
                af[i] = *(const bf16x8_t*)(&As[wm + i * 16 + l16][kk + quad * 8]);
            #pragma unroll
            for (int j = 0; j < 4; ++j)
                bfr[j] = *(const bf16x8_t*)(&Bs[wn + j * 16 + l16][kk + quad * 8]);
            #pragma unroll
            for (int i = 0; i < 4; ++i)
                #pragma unroll
                for (int j = 0; j < 4; ++j)
                    acc[i][j] = __builtin_amdgcn_mfma_f32_16x16x32_bf16(af[i], bfr[j], acc[i][j], 0, 0, 0);
        }
        __syncthreads();
    }

    int mbase = bm + wm + quad * 4;
    int nbase = bn + wn + l16;
    #pragma unroll
    for (int i = 0; i < 4; ++i) {
        #pragma unroll
        for (int j = 0; j < 4; ++j) {
            int n = nbase + j * 16;
            if (mode == 0) {
                #pragma unroll
                for (int r = 0; r < 4; ++r)
                    Cout[(size_t)(mbase + i * 16 + r) * ldc + n] = acc[i][j][r];
            } else if (mode == 1) {
                #pragma unroll
                for (int r = 0; r < 4; ++r)
                    Cout[(size_t)(mbase + i * 16 + r) * ldc + n] += acc[i][j][r];
            } else {
                float bv = bias[n];
                #pragma unroll
                for (int r = 0; r < 4; ++r) {
                    float v = acc[i][j][r] + bv;
                    Cout[(size_t)(mbase + i * 16 + r) * ldc + n] = (v > 20.f) ? v : log1pf(__expf(v));
                }
            }
        }
    }
}

// ---------------- causal conv4 + bias + silu ----------------
__global__ __launch_bounds__(256) void conv_silu_kernel(
    const float* __restrict__ xz, const float* __restrict__ cw, const float* __restrict__ cb,
    float* __restrict__ xconv) {
    int idx = blockIdx.x * 256 + threadIdx.x;  // < B*L*DINNER
    int d = idx % DINNER;
    int bl = idx / DINNER;
    int l = bl % LSEQ;
    int b = bl / LSEQ;
    float acc = cb[d];
    #pragma unroll
    for (int k = 0; k < DCONV; ++k) {
        int lp = l - (DCONV - 1) + k;
        if (lp >= 0)
            acc += xz[((size_t)(b * LSEQ + lp)) * (2 * DINNER) + d] * cw[d * DCONV + k];
    }
    float s = acc / (1.f + __expf(-acc));
    xconv[idx] = s;
}

// ================= chunked selective scan =================
__global__ __launch_bounds__(256) void scan_phaseA(
    const float* __restrict__ delta, const float* __restrict__ xconv,
    const float* __restrict__ xdbl, const float* __restrict__ A_log,
    float* __restrict__ Psum, float* __restrict__ Ssum) {
    int gtid = blockIdx.x * 256 + threadIdx.x;  // < B*NCHUNK*DINNER
    int d = gtid % DINNER;
    int c = (gtid / DINNER) % NCHUNK;
    int b = gtid / (DINNER * NCHUNK);
    float Av[DSTATE], P[DSTATE], S[DSTATE];
    #pragma unroll
    for (int s = 0; s < DSTATE; ++s) {
        Av[s] = -__expf(A_log[d * DSTATE + s]);
        P[s] = 1.f; S[s] = 0.f;
    }
    int t0 = c * CLEN;
    for (int i = 0; i < CLEN; ++i) {
        size_t row = (size_t)b * LSEQ + t0 + i;
        float dl = delta[row * DINNER + d];
        float u  = xconv[row * DINNER + d];
        float bt = dl * u;
        const float4* Bp = (const float4*)(xdbl + row * XDSTR + DTRANK);
        float4 B0 = Bp[0], B1 = Bp[1], B2 = Bp[2], B3 = Bp[3];
        float Bv[DSTATE] = {B0.x,B0.y,B0.z,B0.w, B1.x,B1.y,B1.z,B1.w,
                            B2.x,B2.y,B2.z,B2.w, B3.x,B3.y,B3.z,B3.w};
        #pragma unroll
        for (int s = 0; s < DSTATE; ++s) {
            float a = __expf(dl * Av[s]);
            P[s] *= a;
            S[s] = a * S[s] + bt * Bv[s];
        }
    }
    size_t base = ((size_t)(b * NCHUNK + c) * DSTATE) * DINNER + d;
    #pragma unroll
    for (int s = 0; s < DSTATE; ++s) {
        Psum[base + (size_t)s * DINNER] = P[s];
        Ssum[base + (size_t)s * DINNER] = S[s];
    }
}

__global__ __launch_bounds__(256) void scan_phaseB(
    const float* __restrict__ Psum, const float* __restrict__ Ssum,
    float* __restrict__ Hin) {
    int gtid = blockIdx.x * 256 + threadIdx.x;  // < B*DSTATE*DINNER
    int d = gtid % DINNER;
    int s = (gtid / DINNER) % DSTATE;
    int b = gtid / (DINNER * DSTATE);
    float h = 0.f;
    for (int c = 0; c < NCHUNK; ++c) {
        size_t idx = ((size_t)(b * NCHUNK + c) * DSTATE + s) * DINNER + d;
        Hin[idx] = h;
        h = Psum[idx] * h + Ssum[idx];
    }
}

__global__ __launch_bounds__(256) void scan_phaseC(
    const float* __restrict__ delta, const float* __restrict__ xconv,
    const float* __restrict__ xdbl, const float* __restrict__ xz,
    const float* __restrict__ A_log, const float* __restrict__ D_skip,
    const float* __restrict__ Hin, float* __restrict__ y) {
    int gtid = blockIdx.x * 256 + threadIdx.x;  // < B*NCHUNK*DINNER
    int d = gtid % DINNER;
    int c = (gtid / DINNER) % NCHUNK;
    int b = gtid / (DINNER * NCHUNK);
    float Av[DSTATE], h[DSTATE];
    size_t base = ((size_t)(b * NCHUNK + c) * DSTATE) * DINNER + d;
    #pragma unroll
    for (int s = 0; s < DSTATE; ++s) {
        Av[s] = -__expf(A_log[d * DSTATE + s]);
        h[s] = Hin[base + (size_t)s * DINNER];
    }
    float Dsk = D_skip[d];
    int t0 = c * CLEN;
    for (int i = 0; i < CLEN; ++i) {
        size_t row = (size_t)b * LSEQ + t0 + i;
        float dl = delta[row * DINNER + d];
        float u  = xconv[row * DINNER + d];
        float bt = dl * u;
        const float4* Bp = (const float4*)(xdbl + row * XDSTR + DTRANK);
        float4 B0 = Bp[0], B1 = Bp[1], B2 = Bp[2], B3 = Bp[3];
        const float4* Cp = (const float4*)(xdbl + row * XDSTR + DTRANK + DSTATE);
        float4 C0 = Cp[0], C1 = Cp[1], C2 = Cp[2], C3 = Cp[3];
        float Bv[DSTATE] = {B0.x,B0.y,B0.z,B0.w, B1.x,B1.y,B1.z,B1.w,
                            B2.x,B2.y,B2.z,B2.w, B3.x,B3.y,B3.z,B3.w};
        float Cv[DSTATE] = {C0.x,C0.y,C0.z,C0.w, C1.x,C1.y,C1.z,C1.w,
                            C2.x,C2.y,C2.z,C2.w, C3.x,C3.y,C3.z,C3.w};
        float acc = 0.f;
        #pragma unroll
        for (int s = 0; s < DSTATE; ++s) {
            float a = __expf(dl * Av[s]);
            h[s] = a * h[s] + bt * Bv[s];
            acc += h[s] * Cv[s];
        }
        float zv = xz[row * (2 * DINNER) + DINNER + d];
        float sz = zv / (1.f + __expf(-zv));
        y[row * DINNER + d] = (acc + u * Dsk) * sz;
    }
}

// ---------------- final: last-token rmsnorm ----------------
__global__ __launch_bounds__(256) void final_kernel(
    const float* __restrict__ res, const int* __restrict__ mask,
    const float* __restrict__ w, float* __restrict__ out) {
    __shared__ float sbuf[8];
    int b = blockIdx.x;
    float cnt = 0.f;
    for (int i = threadIdx.x; i < LSEQ; i += 256) cnt += (float)mask[b * LSEQ + i];
    cnt = block_reduce_sum(cnt, sbuf);
    int last = (int)cnt - 1;
    const float* x = res + ((size_t)b * LSEQ + last) * DMODEL;
    float ss = 0.f;
    for (int i = threadIdx.x; i < DMODEL; i += 256) { float v = x[i]; ss += v * v; }
    ss = block_reduce_sum(ss, sbuf);
    float scale = rsqrtf(ss / (float)DMODEL + 1e-5f);
    for (int i = threadIdx.x; i < DMODEL; i += 256)
        out[b * DMODEL + i] = x[i] * scale * w[i];
}

extern "C" void kernel_launch(void* const* d_in, const int* in_sizes, int n_in,
                              void* d_out, int out_size, void* d_ws, size_t ws_size,
                              hipStream_t stream) {
    const int*   seq      = (const int*)d_in[0];
    const int*   mask     = (const int*)d_in[1];
    const float* emb      = (const float*)d_in[2];
    const float* norm_w   = (const float*)d_in[3];
    const float* in_w     = (const float*)d_in[4];
    const float* conv_w   = (const float*)d_in[5];
    const float* conv_b   = (const float*)d_in[6];
    const float* xp_w     = (const float*)d_in[7];
    const float* dt_w     = (const float*)d_in[8];
    const float* dt_b     = (const float*)d_in[9];
    const float* A_log    = (const float*)d_in[10];
    const float* D_skip   = (const float*)d_in[11];
    const float* out_w    = (const float*)d_in[12];
    const float* normf_w  = (const float*)d_in[13];
    float* out = (float*)d_out;

    char* ws = (char*)d_ws;
    float* residual = (float*)(ws);                      // 6291456
    float* hn       = (float*)(ws + 6291456);            // 6291456
    float* xz       = (float*)(ws + 12582912);           // 25165824
    float* xconv    = (float*)(ws + 37748736);           // 12582912
    float* xdbl     = (float*)(ws + 50331648);           // 2048*128*4 = 1048576
    float* delta    = (float*)(ws + 51380224);           // 12582912
    float* ybuf     = (float*)(ws + 63963136);           // 12582912
    float* Psum     = (float*)(ws + 76546048);           // 12582912
    float* Ssum     = (float*)(ws + 89128960);           // 12582912
    float* Hin      = (float*)(ws + 101711872);          // 12582912
    float* xp_pad   = (float*)(ws + 114294784);          // 3145728
    float* dt_pad   = (float*)(ws + 117440512);          // 1572864
                                                         // total 119013376 bytes

    embed_kernel<<<6144, 256, 0, stream>>>(seq, emb, residual);
    pad_xp_kernel<<<3072, 256, 0, stream>>>(xp_w, xp_pad);
    pad_dt_kernel<<<1536, 256, 0, stream>>>(dt_w, dt_pad);

    for (int i = 0; i < NLAYER; ++i) {
        rmsnorm_kernel<<<BSZ * LSEQ, 256, 0, stream>>>(residual, norm_w + (size_t)i * DMODEL, hn);
        // in_proj: (2048 x 3072) = hn (2048x768) @ in_w^T
        gemm128<<<dim3(16, 24), 256, 0, stream>>>(
            hn, DMODEL, in_w + (size_t)i * 2 * DINNER * DMODEL, DMODEL,
            xz, 2 * DINNER, nullptr, 2048, 3072, DMODEL, 0);
        conv_silu_kernel<<<12288, 256, 0, stream>>>(
            xz, conv_w + (size_t)i * DINNER * DCONV, conv_b + (size_t)i * DINNER, xconv);
        // x_proj: (2048 x 128pad) = xconv (2048x1536) @ xp_pad^T  (64-tile: N small)
        gemm_nt<<<dim3(32, 2), 256, 0, stream>>>(
            xconv, DINNER, xp_pad + (size_t)i * 128 * DINNER, DINNER,
            xdbl, XDSTR, nullptr, 2048, 128, DINNER, 0);
        // dt_proj + softplus: delta (2048x1536) = xdbl[:, :64pad] @ dt_pad^T
        gemm128<<<dim3(16, 12), 256, 0, stream>>>(
            xdbl, XDSTR, dt_pad + (size_t)i * DINNER * 64, 64,
            delta, DINNER, dt_b + (size_t)i * DINNER, 2048, DINNER, 64, 2);
        scan_phaseA<<<768, 256, 0, stream>>>(
            delta, xconv, xdbl, A_log + (size_t)i * DINNER * DSTATE, Psum, Ssum);
        scan_phaseB<<<192, 256, 0, stream>>>(Psum, Ssum, Hin);
        scan_phaseC<<<768, 256, 0, stream>>>(
            delta, xconv, xdbl, xz, A_log + (size_t)i * DINNER * DSTATE,
            D_skip + (size_t)i * DINNER, Hin, ybuf);
        // out_proj accumulate into residual
        gemm128<<<dim3(16, 6), 256, 0, stream>>>(
            ybuf, DINNER, out_w + (size_t)i * DMODEL * DINNER, DINNER,
            residual, DMODEL, nullptr, 2048, DMODEL, DINNER, 1);
    }

    final_kernel<<<BSZ, 256, 0, stream>>>(residual, mask, normf_w, out);
}

// Round 6
// 963.481 us; speedup vs baseline: 1.4107x; 1.4107x over previous
//
#include <hip/hip_runtime.h>
#include <hip/hip_bf16.h>

// ---- problem constants ----
#define BSZ 2
#define LSEQ 1024
#define DMODEL 768
#define NLAYER 4
#define DINNER 1536
#define DSTATE 16
#define DCONV 4
#define DTRANK 48
#define NCHUNK 64
#define CLEN 16
#define XDSTR 128

typedef __bf16 bf16x8_t __attribute__((ext_vector_type(8)));
typedef float f32x4_t __attribute__((ext_vector_type(4)));
typedef __hip_bfloat16 bf16;

// ---------------- block reduce ----------------
__device__ inline float block_reduce_sum(float v, float* sbuf) {
    __syncthreads();
    #pragma unroll
    for (int o = 32; o > 0; o >>= 1) v += __shfl_down(v, o, 64);
    int wid = threadIdx.x >> 6;
    int lane = threadIdx.x & 63;
    if (lane == 0) sbuf[wid] = v;
    __syncthreads();
    if (threadIdx.x == 0) sbuf[0] = (sbuf[0] + sbuf[1]) + (sbuf[2] + sbuf[3]);
    __syncthreads();
    return sbuf[0];
}

// ---------------- embedding ----------------
__global__ __launch_bounds__(256) void embed_kernel(
    const int* __restrict__ seq, const float* __restrict__ emb, float* __restrict__ res) {
    int idx = blockIdx.x * 256 + threadIdx.x;
    int bl = idx / DMODEL;
    int dd = idx - bl * DMODEL;
    res[idx] = emb[(size_t)seq[bl] * DMODEL + dd];
}

// ---------------- per-layer weight prep: f32 -> bf16 (+padding) ----------------
// ranges: in_w 3072*768 | out_w 768*1536 | xp pad 128*1536 | dt pad 1536*64
#define PREP_N1 (3072*768)
#define PREP_N2 (768*1536)
#define PREP_N3 (128*1536)
#define PREP_N4 (1536*64)
__global__ __launch_bounds__(256) void prep_layer(
    const float* __restrict__ in_w, const float* __restrict__ out_w,
    const float* __restrict__ xp_w, const float* __restrict__ dt_w,
    bf16* __restrict__ in16, bf16* __restrict__ out16,
    bf16* __restrict__ xp16, bf16* __restrict__ dt16) {
    int idx = blockIdx.x * 256 + threadIdx.x;
    if (idx < PREP_N1) { in16[idx] = __float2bfloat16(in_w[idx]); return; }
    idx -= PREP_N1;
    if (idx < PREP_N2) { out16[idx] = __float2bfloat16(out_w[idx]); return; }
    idx -= PREP_N2;
    if (idx < PREP_N3) {
        int k = idx % DINNER, e = idx / DINNER;
        xp16[idx] = (e < 80) ? __float2bfloat16(xp_w[(size_t)e * DINNER + k]) : __float2bfloat16(0.f);
        return;
    }
    idx -= PREP_N3;
    if (idx < PREP_N4) {
        int k = idx % 64, d = idx / 64;
        dt16[idx] = (k < DTRANK) ? __float2bfloat16(dt_w[(size_t)d * DTRANK + k]) : __float2bfloat16(0.f);
    }
}

// ---------------- rmsnorm -> bf16 ----------------
__global__ __launch_bounds__(256) void rmsnorm_kernel(
    const float* __restrict__ res, const float* __restrict__ w, bf16* __restrict__ out) {
    __shared__ float sbuf[8];
    int row = blockIdx.x;
    const float* x = res + (size_t)row * DMODEL;
    float ss = 0.f;
    for (int i = threadIdx.x; i < DMODEL; i += 256) { float v = x[i]; ss += v * v; }
    ss = block_reduce_sum(ss, sbuf);
    float scale = rsqrtf(ss / (float)DMODEL + 1e-5f);
    for (int i = threadIdx.x; i < DMODEL; i += 256)
        out[(size_t)row * DMODEL + i] = __float2bfloat16(x[i] * scale * w[i]);
}

// ---------------- GEMM NT, bf16 inputs, 64x64 tile, optional split-K ----------------
// A: M x K bf16 (row stride lda); Bw: N x K bf16 (row stride ldb).
// mode 0: C = acc (+ optional bf16 C16); mode 1: atomicAdd into C; mode 2: softplus(acc+bias[n]).
// grid.z = K-splits (K % (64*gridDim.z) == 0).
__global__ __launch_bounds__(256) void gemm_bt(
    const bf16* __restrict__ A, int lda, const bf16* __restrict__ Bw, int ldb,
    float* __restrict__ Cout, int ldc, bf16* __restrict__ C16,
    const float* __restrict__ bias, int K, int mode) {
    __shared__ bf16 As[64][72];
    __shared__ bf16 Bs[64][72];
    int tid = threadIdx.x;
    int wave = tid >> 6;
    int lane = tid & 63;
    int quad = lane >> 4;
    int l16 = lane & 15;
    int bm = blockIdx.x * 64;
    int bn = blockIdx.y * 64;
    int lrow = tid >> 2;           // 0..63
    int lk = (tid & 3) * 16;       // 0,16,32,48 (bf16 elems)
    int kpb = K / gridDim.z;
    int kbeg = blockIdx.z * kpb;
    int kend = kbeg + kpb;

    f32x4_t acc[4];
    #pragma unroll
    for (int i = 0; i < 4; ++i) acc[i] = (f32x4_t){0.f, 0.f, 0.f, 0.f};

    for (int k0 = kbeg; k0 < kend; k0 += 64) {
        const bf16* ag = A + (size_t)(bm + lrow) * lda + k0 + lk;
        const bf16* bg = Bw + (size_t)(bn + lrow) * ldb + k0 + lk;
        *(int4*)&As[lrow][lk]     = *(const int4*)(ag);
        *(int4*)&As[lrow][lk + 8] = *(const int4*)(ag + 8);
        *(int4*)&Bs[lrow][lk]     = *(const int4*)(bg);
        *(int4*)&Bs[lrow][lk + 8] = *(const int4*)(bg + 8);
        __syncthreads();
        #pragma unroll
        for (int kk = 0; kk < 64; kk += 32) {
            bf16x8_t af = *(const bf16x8_t*)(&As[wave * 16 + l16][kk + quad * 8]);
            #pragma unroll
            for (int i = 0; i < 4; ++i) {
                bf16x8_t bfv = *(const bf16x8_t*)(&Bs[i * 16 + l16][kk + quad * 8]);
                acc[i] = __builtin_amdgcn_mfma_f32_16x16x32_bf16(af, bfv, acc[i], 0, 0, 0);
            }
        }
        __syncthreads();
    }

    int m0 = bm + wave * 16 + quad * 4;
    #pragma unroll
    for (int i = 0; i < 4; ++i) {
        int n = bn + i * 16 + l16;
        if (mode == 0) {
            #pragma unroll
            for (int r = 0; r < 4; ++r) {
                Cout[(size_t)(m0 + r) * ldc + n] = acc[i][r];
                if (C16) C16[(size_t)(m0 + r) * ldc + n] = __float2bfloat16(acc[i][r]);
            }
        } else if (mode == 1) {
            #pragma unroll
            for (int r = 0; r < 4; ++r)
                atomicAdd(&Cout[(size_t)(m0 + r) * ldc + n], acc[i][r]);
        } else {
            float bv = bias[n];
            #pragma unroll
            for (int r = 0; r < 4; ++r) {
                float v = acc[i][r] + bv;
                Cout[(size_t)(m0 + r) * ldc + n] = (v > 20.f) ? v : log1pf(__expf(v));
            }
        }
    }
}

// ---------------- causal conv4 + bias + silu -> bf16 ----------------
__global__ __launch_bounds__(256) void conv_silu_kernel(
    const float* __restrict__ xz, const float* __restrict__ cw, const float* __restrict__ cb,
    bf16* __restrict__ xconv16) {
    int idx = blockIdx.x * 256 + threadIdx.x;  // < B*L*DINNER
    int d = idx % DINNER;
    int bl = idx / DINNER;
    int l = bl % LSEQ;
    int b = bl / LSEQ;
    float acc = cb[d];
    #pragma unroll
    for (int k = 0; k < DCONV; ++k) {
        int lp = l - (DCONV - 1) + k;
        if (lp >= 0)
            acc += xz[((size_t)(b * LSEQ + lp)) * (2 * DINNER) + d] * cw[d * DCONV + k];
    }
    float s = acc / (1.f + __expf(-acc));
    xconv16[idx] = __float2bfloat16(s);
}

// ================= chunked selective scan =================
__global__ __launch_bounds__(256) void scan_phaseA(
    const float* __restrict__ delta, const bf16* __restrict__ xconv16,
    const float* __restrict__ xdbl, const float* __restrict__ A_log,
    float* __restrict__ Psum, float* __restrict__ Ssum) {
    int gtid = blockIdx.x * 256 + threadIdx.x;  // < B*NCHUNK*DINNER
    int d = gtid % DINNER;
    int c = (gtid / DINNER) % NCHUNK;
    int b = gtid / (DINNER * NCHUNK);
    float Av[DSTATE], P[DSTATE], S[DSTATE];
    #pragma unroll
    for (int s = 0; s < DSTATE; ++s) {
        Av[s] = -__expf(A_log[d * DSTATE + s]);
        P[s] = 1.f; S[s] = 0.f;
    }
    int t0 = c * CLEN;
    for (int i = 0; i < CLEN; ++i) {
        size_t row = (size_t)b * LSEQ + t0 + i;
        float dl = delta[row * DINNER + d];
        float u  = __bfloat162float(xconv16[row * DINNER + d]);
        float bt = dl * u;
        const float4* Bp = (const float4*)(xdbl + row * XDSTR + DTRANK);
        float4 B0 = Bp[0], B1 = Bp[1], B2 = Bp[2], B3 = Bp[3];
        float Bv[DSTATE] = {B0.x,B0.y,B0.z,B0.w, B1.x,B1.y,B1.z,B1.w,
                            B2.x,B2.y,B2.z,B2.w, B3.x,B3.y,B3.z,B3.w};
        #pragma unroll
        for (int s = 0; s < DSTATE; ++s) {
            float a = __expf(dl * Av[s]);
            P[s] *= a;
            S[s] = a * S[s] + bt * Bv[s];
        }
    }
    size_t base = ((size_t)(b * NCHUNK + c) * DSTATE) * DINNER + d;
    #pragma unroll
    for (int s = 0; s < DSTATE; ++s) {
        Psum[base + (size_t)s * DINNER] = P[s];
        Ssum[base + (size_t)s * DINNER] = S[s];
    }
}

__global__ __launch_bounds__(256) void scan_phaseB(
    const float* __restrict__ Psum, const float* __restrict__ Ssum,
    float* __restrict__ Hin) {
    int gtid = blockIdx.x * 256 + threadIdx.x;  // < B*DSTATE*DINNER
    int d = gtid % DINNER;
    int s = (gtid / DINNER) % DSTATE;
    int b = gtid / (DINNER * DSTATE);
    float h = 0.f;
    for (int c = 0; c < NCHUNK; ++c) {
        size_t idx = ((size_t)(b * NCHUNK + c) * DSTATE + s) * DINNER + d;
        Hin[idx] = h;
        h = Psum[idx] * h + Ssum[idx];
    }
}

__global__ __launch_bounds__(256) void scan_phaseC(
    const float* __restrict__ delta, const bf16* __restrict__ xconv16,
    const float* __restrict__ xdbl, const float* __restrict__ xz,
    const float* __restrict__ A_log, const float* __restrict__ D_skip,
    const float* __restrict__ Hin, bf16* __restrict__ y16) {
    int gtid = blockIdx.x * 256 + threadIdx.x;  // < B*NCHUNK*DINNER
    int d = gtid % DINNER;
    int c = (gtid / DINNER) % NCHUNK;
    int b = gtid / (DINNER * NCHUNK);
    float Av[DSTATE], h[DSTATE];
    size_t base = ((size_t)(b * NCHUNK + c) * DSTATE) * DINNER + d;
    #pragma unroll
    for (int s = 0; s < DSTATE; ++s) {
        Av[s] = -__expf(A_log[d * DSTATE + s]);
        h[s] = Hin[base + (size_t)s * DINNER];
    }
    float Dsk = D_skip[d];
    int t0 = c * CLEN;
    for (int i = 0; i < CLEN; ++i) {
        size_t row = (size_t)b * LSEQ + t0 + i;
        float dl = delta[row * DINNER + d];
        float u  = __bfloat162float(xconv16[row * DINNER + d]);
        float bt = dl * u;
        const float4* Bp = (const float4*)(xdbl + row * XDSTR + DTRANK);
        float4 B0 = Bp[0], B1 = Bp[1], B2 = Bp[2], B3 = Bp[3];
        const float4* Cp = (const float4*)(xdbl + row * XDSTR + DTRANK + DSTATE);
        float4 C0 = Cp[0], C1 = Cp[1], C2 = Cp[2], C3 = Cp[3];
        float Bv[DSTATE] = {B0.x,B0.y,B0.z,B0.w, B1.x,B1.y,B1.z,B1.w,
                            B2.x,B2.y,B2.z,B2.w, B3.x,B3.y,B3.z,B3.w};
        float Cv[DSTATE] = {C0.x,C0.y,C0.z,C0.w, C1.x,C1.y,C1.z,C1.w,
                            C2.x,C2.y,C2.z,C2.w, C3.x,C3.y,C3.z,C3.w};
        float acc = 0.f;
        #pragma unroll
        for (int s = 0; s < DSTATE; ++s) {
            float a = __expf(dl * Av[s]);
            h[s] = a * h[s] + bt * Bv[s];
            acc += h[s] * Cv[s];
        }
        float zv = xz[row * (2 * DINNER) + DINNER + d];
        float sz = zv / (1.f + __expf(-zv));
        y16[row * DINNER + d] = __float2bfloat16((acc + u * Dsk) * sz);
    }
}

// ---------------- final: last-token rmsnorm ----------------
__global__ __launch_bounds__(256) void final_kernel(
    const float* __restrict__ res, const int* __restrict__ mask,
    const float* __restrict__ w, float* __restrict__ out) {
    __shared__ float sbuf[8];
    int b = blockIdx.x;
    float cnt = 0.f;
    for (int i = threadIdx.x; i < LSEQ; i += 256) cnt += (float)mask[b * LSEQ + i];
    cnt = block_reduce_sum(cnt, sbuf);
    int last = (int)cnt - 1;
    const float* x = res + ((size_t)b * LSEQ + last) * DMODEL;
    float ss = 0.f;
    for (int i = threadIdx.x; i < DMODEL; i += 256) { float v = x[i]; ss += v * v; }
    ss = block_reduce_sum(ss, sbuf);
    float scale = rsqrtf(ss / (float)DMODEL + 1e-5f);
    for (int i = threadIdx.x; i < DMODEL; i += 256)
        out[b * DMODEL + i] = x[i] * scale * w[i];
}

extern "C" void kernel_launch(void* const* d_in, const int* in_sizes, int n_in,
                              void* d_out, int out_size, void* d_ws, size_t ws_size,
                              hipStream_t stream) {
    const int*   seq      = (const int*)d_in[0];
    const int*   mask     = (const int*)d_in[1];
    const float* emb      = (const float*)d_in[2];
    const float* norm_w   = (const float*)d_in[3];
    const float* in_w     = (const float*)d_in[4];
    const float* conv_w   = (const float*)d_in[5];
    const float* conv_b   = (const float*)d_in[6];
    const float* xp_w     = (const float*)d_in[7];
    const float* dt_w     = (const float*)d_in[8];
    const float* dt_b     = (const float*)d_in[9];
    const float* A_log    = (const float*)d_in[10];
    const float* D_skip   = (const float*)d_in[11];
    const float* out_w    = (const float*)d_in[12];
    const float* normf_w  = (const float*)d_in[13];
    float* out = (float*)d_out;

    char* ws = (char*)d_ws;
    float* residual = (float*)(ws);                      // 6291456
    bf16*  hn16     = (bf16*)(ws + 6291456);             // 3145728
    float* xz       = (float*)(ws + 9437184);            // 25165824
    bf16*  xconv16  = (bf16*)(ws + 34603008);            // 6291456
    float* xdbl     = (float*)(ws + 40894464);           // 1048576
    bf16*  xdbl16   = (bf16*)(ws + 41943040);            // 524288
    float* delta    = (float*)(ws + 42467328);           // 12582912
    bf16*  ybuf16   = (bf16*)(ws + 55050240);            // 6291456
    float* Psum     = (float*)(ws + 61341696);           // 12582912
    float* Ssum     = (float*)(ws + 73924608);           // 12582912
    float* Hin      = (float*)(ws + 86507520);           // 12582912
    bf16*  in16     = (bf16*)(ws + 99090432);            // 4718592
    bf16*  out16    = (bf16*)(ws + 103809024);           // 2359296
    bf16*  xp16     = (bf16*)(ws + 106168320);           // 393216
    bf16*  dt16     = (bf16*)(ws + 106561536);           // 196608
                                                         // total 106758144 bytes

    embed_kernel<<<6144, 256, 0, stream>>>(seq, emb, residual);

    for (int i = 0; i < NLAYER; ++i) {
        prep_layer<<<(PREP_N1 + PREP_N2 + PREP_N3 + PREP_N4 + 255) / 256, 256, 0, stream>>>(
            in_w + (size_t)i * 2 * DINNER * DMODEL, out_w + (size_t)i * DMODEL * DINNER,
            xp_w + (size_t)i * 80 * DINNER, dt_w + (size_t)i * DINNER * DTRANK,
            in16, out16, xp16, dt16);
        rmsnorm_kernel<<<BSZ * LSEQ, 256, 0, stream>>>(residual, norm_w + (size_t)i * DMODEL, hn16);
        // in_proj: xz(2048x3072) = hn16 @ in16^T
        gemm_bt<<<dim3(32, 48, 1), 256, 0, stream>>>(
            hn16, DMODEL, in16, DMODEL, xz, 2 * DINNER, nullptr, nullptr, DMODEL, 0);
        conv_silu_kernel<<<12288, 256, 0, stream>>>(
            xz, conv_w + (size_t)i * DINNER * DCONV, conv_b + (size_t)i * DINNER, xconv16);
        // x_proj: xdbl(2048x128) = xconv16 @ xp16^T (dual f32+bf16 output)
        gemm_bt<<<dim3(32, 2, 1), 256, 0, stream>>>(
            xconv16, DINNER, xp16, DINNER, xdbl, XDSTR, xdbl16, nullptr, DINNER, 0);
        // dt_proj + softplus: delta(2048x1536) = xdbl16[:, :64] @ dt16^T
        gemm_bt<<<dim3(32, 24, 1), 256, 0, stream>>>(
            xdbl16, XDSTR, dt16, 64, delta, DINNER, nullptr, dt_b + (size_t)i * DINNER, 64, 2);
        scan_phaseA<<<768, 256, 0, stream>>>(
            delta, xconv16, xdbl, A_log + (size_t)i * DINNER * DSTATE, Psum, Ssum);
        scan_phaseB<<<192, 256, 0, stream>>>(Psum, Ssum, Hin);
        scan_phaseC<<<768, 256, 0, stream>>>(
            delta, xconv16, xdbl, xz, A_log + (size_t)i * DINNER * DSTATE,
            D_skip + (size_t)i * DINNER, Hin, ybuf16);
        // out_proj: residual += ybuf16 @ out16^T, split-K=2, atomic accumulate
        gemm_bt<<<dim3(32, 12, 2), 256, 0, stream>>>(
            ybuf16, DINNER, out16, DINNER, residual, DMODEL, nullptr, nullptr, DINNER, 1);
    }

    final_kernel<<<BSZ, 256, 0, stream>>>(residual, mask, normf_w, out);
}